// Round 1
// baseline (9667.777 us; speedup 1.0000x reference)
//
#include <hip/hip_runtime.h>

#define NBATCH 128
#define NDIM 512
static constexpr size_t MAT = (size_t)NDIM * NDIM;      // 262144
static constexpr size_t BATMAT = (size_t)NBATCH * MAT;  // 33554432 floats
#define SIGMA_F 1e-6f

// =====================================================================
// GEMM: C[i][j] = alpha * sum_k OpA(k,i)*OpB(k,j)
//   OpA(k,i) = TA ? A[i*N+k] : A[k*N+i];   OpB(k,j) = B[k*N+j]
//   SYM=1: compute lower tiles (by>=bx) only, mirror into upper.
// =====================================================================
template <int TA, int SYM>
__global__ __launch_bounds__(256) void gemm512(const float* __restrict__ Ag,
                                               const float* __restrict__ Bg,
                                               float* __restrict__ Cg,
                                               const float* __restrict__ alphaPtr) {
  const int b = blockIdx.z;
  const float* Ab = Ag + (size_t)b * MAT;
  const float* Bb = Bg + (size_t)b * MAT;
  float* Cb = Cg + (size_t)b * MAT;
  int bx, by;
  if (SYM) {
    int t = blockIdx.x;
    by = 0;
    while ((by + 1) * (by + 2) / 2 <= t) ++by;
    bx = t - by * (by + 1) / 2;
  } else {
    bx = blockIdx.x;
    by = blockIdx.y;
  }
  const int i0 = by * 64, j0 = bx * 64;
  __shared__ float As[32][68];
  __shared__ float Bs[32][68];
  const int tid = threadIdx.x;
  const int tx = tid & 15, ty = tid >> 4;
  float acc[4][4] = {};
  for (int k0 = 0; k0 < NDIM; k0 += 32) {
    if (TA == 0) {
      const int kk = tid >> 4, m4 = (tid & 15) << 2;
#pragma unroll
      for (int pp = 0; pp < 2; ++pp) {
        float4 v = *reinterpret_cast<const float4*>(&Ab[(size_t)(k0 + kk + 16 * pp) * NDIM + i0 + m4]);
        *reinterpret_cast<float4*>(&As[kk + 16 * pp][m4]) = v;
      }
    } else {
      const int m = tid >> 3, kq = (tid & 7) << 2;
#pragma unroll
      for (int pp = 0; pp < 2; ++pp) {
        float4 v = *reinterpret_cast<const float4*>(&Ab[(size_t)(i0 + m + 32 * pp) * NDIM + k0 + kq]);
        As[kq + 0][m + 32 * pp] = v.x;
        As[kq + 1][m + 32 * pp] = v.y;
        As[kq + 2][m + 32 * pp] = v.z;
        As[kq + 3][m + 32 * pp] = v.w;
      }
    }
    {
      const int kk = tid >> 4, n4 = (tid & 15) << 2;
#pragma unroll
      for (int pp = 0; pp < 2; ++pp) {
        float4 v = *reinterpret_cast<const float4*>(&Bb[(size_t)(k0 + kk + 16 * pp) * NDIM + j0 + n4]);
        *reinterpret_cast<float4*>(&Bs[kk + 16 * pp][n4]) = v;
      }
    }
    __syncthreads();
#pragma unroll
    for (int kk = 0; kk < 32; ++kk) {
      float4 a = *reinterpret_cast<const float4*>(&As[kk][ty << 2]);
      float4 bv = *reinterpret_cast<const float4*>(&Bs[kk][tx << 2]);
      acc[0][0] += a.x * bv.x; acc[0][1] += a.x * bv.y; acc[0][2] += a.x * bv.z; acc[0][3] += a.x * bv.w;
      acc[1][0] += a.y * bv.x; acc[1][1] += a.y * bv.y; acc[1][2] += a.y * bv.z; acc[1][3] += a.y * bv.w;
      acc[2][0] += a.z * bv.x; acc[2][1] += a.z * bv.y; acc[2][2] += a.z * bv.z; acc[2][3] += a.z * bv.w;
      acc[3][0] += a.w * bv.x; acc[3][1] += a.w * bv.y; acc[3][2] += a.w * bv.z; acc[3][3] += a.w * bv.w;
    }
    __syncthreads();
  }
  const float alpha = alphaPtr ? alphaPtr[b] : 1.0f;
#pragma unroll
  for (int r = 0; r < 4; ++r) {
    float4 o = make_float4(alpha * acc[r][0], alpha * acc[r][1], alpha * acc[r][2], alpha * acc[r][3]);
    *reinterpret_cast<float4*>(&Cb[(size_t)(i0 + (ty << 2) + r) * NDIM + j0 + (tx << 2)]) = o;
  }
  if (SYM && bx != by) {
#pragma unroll
    for (int r = 0; r < 4; ++r)
#pragma unroll
      for (int c = 0; c < 4; ++c)
        Cb[(size_t)(j0 + (tx << 2) + c) * NDIM + i0 + (ty << 2) + r] = alpha * acc[r][c];
  }
}

// =====================================================================
// rho[b] = clip( ||Q||_F / ||ATA||_F , 1e-6, 1e6 )   ((n_A/n_x)^0.5 == 1)
// =====================================================================
__global__ __launch_bounds__(512) void norms_rho(const float* __restrict__ Q,
                                                 const float* __restrict__ ATA,
                                                 float* __restrict__ rho) {
  const int b = blockIdx.x;
  const int tid = threadIdx.x;
  const float* Qb = Q + (size_t)b * MAT;
  const float* Tb = ATA + (size_t)b * MAT;
  double sq = 0.0, st = 0.0;
  for (int e = tid; e < (int)MAT; e += 512) {
    float q = Qb[e];
    float t = Tb[e];
    sq += (double)q * q;
    st += (double)t * t;
  }
  __shared__ double s1[512];
  __shared__ double s2[512];
  s1[tid] = sq;
  s2[tid] = st;
  __syncthreads();
  for (int h = 256; h > 0; h >>= 1) {
    if (tid < h) {
      s1[tid] += s1[tid + h];
      s2[tid] += s2[tid + h];
    }
    __syncthreads();
  }
  if (tid == 0) {
    double r = sqrt(s1[0]) / sqrt(s2[0]);
    r = fmin(fmax(r, 1e-6), 1e6);
    rho[b] = (float)r;
  }
}

// =====================================================================
// M = Q + rho*ATA + sigma*I   (in place on the ATA buffer)
// =====================================================================
__global__ void form_m(const float* __restrict__ Q, const float* __restrict__ rho,
                       float* __restrict__ M) {
  size_t stride = (size_t)gridDim.x * blockDim.x;
  for (size_t e = (size_t)blockIdx.x * blockDim.x + threadIdx.x; e < BATMAT; e += stride) {
    int b = (int)(e >> 18);
    int ij = (int)(e & (MAT - 1));
    int i = ij >> 9, j = ij & 511;
    float v = Q[e] + rho[b] * M[e];
    if (i == j) v += SIGMA_F;
    M[e] = v;
  }
}

// =====================================================================
// Batched in-place Cholesky (lower), blocked NB=32, one block per batch.
// =====================================================================
__global__ __launch_bounds__(256) void cholesky512(float* __restrict__ Mg) {
  float* M = Mg + (size_t)blockIdx.x * MAT;
  __shared__ float D[32][33];
  __shared__ float Di[32][33];
  __shared__ float U[64][33];
  __shared__ float V[64][33];
  __shared__ float Ut[32][68];
  __shared__ float Vt[32][68];
  const int tid = threadIdx.x;
  for (int p = 0; p < 16; ++p) {
    const int k0 = p * 32;
    // ---- load + factor diagonal block ----
    for (int e = tid; e < 1024; e += 256) {
      int r = e >> 5, c = e & 31;
      D[r][c] = M[(size_t)(k0 + r) * NDIM + k0 + c];
    }
    __syncthreads();
    for (int j = 0; j < 32; ++j) {
      if (tid == 0) D[j][j] = sqrtf(D[j][j]);
      __syncthreads();
      if (tid > j && tid < 32) D[tid][j] /= D[j][j];
      __syncthreads();
      for (int e = tid; e < 1024; e += 256) {
        int r = e >> 5, c = e & 31;
        if (c > j && c <= r) D[r][c] -= D[r][j] * D[c][j];
      }
      __syncthreads();
    }
    // store factored diag (lower)
    for (int e = tid; e < 1024; e += 256) {
      int r = e >> 5, c = e & 31;
      if (c <= r) M[(size_t)(k0 + r) * NDIM + k0 + c] = D[r][c];
    }
    // ---- Dinv = D^{-1} (lower tri, 32 lanes, column each) ----
    if (tid < 32) {
      int j = tid;
      for (int ii = j; ii < 32; ++ii) {
        float v = (ii == j) ? 1.f : 0.f;
        for (int m = j; m < ii; ++m) v -= D[ii][m] * Di[m][j];
        Di[ii][j] = v / D[ii][ii];
      }
    }
    __syncthreads();
    // ---- panel: L_panel = M_panel * Dinv^T  (fully parallel) ----
    for (int i0 = k0 + 32; i0 < NDIM; i0 += 64) {
      int rows = min(64, NDIM - i0);
      for (int e = tid; e < rows * 32; e += 256) {
        int r = e >> 5, c = e & 31;
        U[r][c] = M[(size_t)(i0 + r) * NDIM + k0 + c];
      }
      __syncthreads();
      for (int e = tid; e < rows * 32; e += 256) {
        int ii = e >> 5, j = e & 31;
        float s = 0.f;
        for (int m = 0; m <= j; ++m) s += U[ii][m] * Di[j][m];
        V[ii][j] = s;
      }
      __syncthreads();
      for (int e = tid; e < rows * 32; e += 256) {
        int r = e >> 5, c = e & 31;
        M[(size_t)(i0 + r) * NDIM + k0 + c] = V[r][c];
      }
      __syncthreads();
    }
    // ---- trailing syrk update: M -= Lp * Lp^T (lower tiles only) ----
    const int base = k0 + 32;
    const int S = NDIM - base;
    const int T = (S + 63) >> 6;
    const int tx = tid & 15, ty = tid >> 4;
    for (int ti = 0; ti < T; ++ti) {
      for (int tj = 0; tj <= ti; ++tj) {
        const int I0 = base + ti * 64, J0 = base + tj * 64;
        __syncthreads();
        for (int e = tid; e < 2048; e += 256) {
          int rr = e >> 5, mm = e & 31;
          Ut[mm][rr] = (I0 + rr < NDIM) ? M[(size_t)(I0 + rr) * NDIM + k0 + mm] : 0.f;
          Vt[mm][rr] = (J0 + rr < NDIM) ? M[(size_t)(J0 + rr) * NDIM + k0 + mm] : 0.f;
        }
        __syncthreads();
        float acc[4][4] = {};
#pragma unroll
        for (int m = 0; m < 32; ++m) {
          float4 a = *reinterpret_cast<const float4*>(&Ut[m][ty << 2]);
          float4 bv = *reinterpret_cast<const float4*>(&Vt[m][tx << 2]);
          acc[0][0] += a.x * bv.x; acc[0][1] += a.x * bv.y; acc[0][2] += a.x * bv.z; acc[0][3] += a.x * bv.w;
          acc[1][0] += a.y * bv.x; acc[1][1] += a.y * bv.y; acc[1][2] += a.y * bv.z; acc[1][3] += a.y * bv.w;
          acc[2][0] += a.z * bv.x; acc[2][1] += a.z * bv.y; acc[2][2] += a.z * bv.z; acc[2][3] += a.z * bv.w;
          acc[3][0] += a.w * bv.x; acc[3][1] += a.w * bv.y; acc[3][2] += a.w * bv.z; acc[3][3] += a.w * bv.w;
        }
#pragma unroll
        for (int r = 0; r < 4; ++r) {
          int gi = I0 + (ty << 2) + r;
          if (gi < NDIM) {
#pragma unroll
            for (int c = 0; c < 4; ++c) {
              int gj = J0 + (tx << 2) + c;
              if (gj < NDIM) M[(size_t)gi * NDIM + gj] -= acc[r][c];
            }
          }
        }
      }
    }
    __syncthreads();
  }
}

// =====================================================================
// Triangular inverse W = L^{-1} (lower). Diag blocks kernel.
// =====================================================================
__global__ __launch_bounds__(256) void trinv_diag(const float* __restrict__ Lg,
                                                  float* __restrict__ Wg) {
  const int b = blockIdx.x;
  const float* L = Lg + (size_t)b * MAT;
  float* W = Wg + (size_t)b * MAT;
  __shared__ float Ld[8][32][33];
  __shared__ float Wd[8][32][33];
  const int g = threadIdx.x >> 5, l = threadIdx.x & 31;
  for (int pass = 0; pass < 2; ++pass) {
    const int bi = pass * 8 + g;
    const int o = bi * 32;
    for (int q = 0; q < 32; ++q) Ld[g][q][l] = L[(size_t)(o + q) * NDIM + o + l];
    __syncthreads();
    for (int ii = l; ii < 32; ++ii) {
      float v = (ii == l) ? 1.f : 0.f;
      for (int m = l; m < ii; ++m) v -= Ld[g][ii][m] * Wd[g][m][l];
      Wd[g][ii][l] = v / Ld[g][ii][ii];
    }
    __syncthreads();
    for (int q = 0; q < 32; ++q)
      if (l <= q) W[(size_t)(o + q) * NDIM + o + l] = Wd[g][q][l];
    __syncthreads();
  }
}

// Off-diagonal blocks: block (J,b) computes column J sequentially over I.
__global__ __launch_bounds__(256) void trinv_offdiag(const float* __restrict__ Lg,
                                                     float* __restrict__ Wg) {
  const int J = blockIdx.x;  // 0..14
  const int b = blockIdx.y;
  const float* L = Lg + (size_t)b * MAT;
  float* W = Wg + (size_t)b * MAT;
  __shared__ float Ls[32][33];
  __shared__ float Ws[32][33];
  __shared__ float Ts[32][33];
  __shared__ float Wi[32][33];
  const int tid = threadIdx.x;
  const int r = tid >> 3, c0 = (tid & 7) << 2;
  for (int I = J + 1; I < 16; ++I) {
    float acc[4] = {0.f, 0.f, 0.f, 0.f};
    for (int K = J; K < I; ++K) {
      __syncthreads();
      for (int e = tid; e < 1024; e += 256) {
        int rr = e >> 5, cc = e & 31;
        Ls[rr][cc] = L[(size_t)(I * 32 + rr) * NDIM + K * 32 + cc];
        Ws[rr][cc] = W[(size_t)(K * 32 + rr) * NDIM + J * 32 + cc];
      }
      __syncthreads();
#pragma unroll 8
      for (int m = 0; m < 32; ++m) {
        float lv = Ls[r][m];
        acc[0] += lv * Ws[m][c0 + 0];
        acc[1] += lv * Ws[m][c0 + 1];
        acc[2] += lv * Ws[m][c0 + 2];
        acc[3] += lv * Ws[m][c0 + 3];
      }
    }
    __syncthreads();
    Ts[r][c0 + 0] = acc[0];
    Ts[r][c0 + 1] = acc[1];
    Ts[r][c0 + 2] = acc[2];
    Ts[r][c0 + 3] = acc[3];
    for (int e = tid; e < 1024; e += 256) {
      int rr = e >> 5, cc = e & 31;
      Wi[rr][cc] = W[(size_t)(I * 32 + rr) * NDIM + I * 32 + cc];
    }
    __syncthreads();
    float o0 = 0.f, o1 = 0.f, o2 = 0.f, o3 = 0.f;
#pragma unroll 8
    for (int m = 0; m < 32; ++m) {
      float wv = Wi[r][m];
      o0 += wv * Ts[m][c0 + 0];
      o1 += wv * Ts[m][c0 + 1];
      o2 += wv * Ts[m][c0 + 2];
      o3 += wv * Ts[m][c0 + 3];
    }
    W[(size_t)(I * 32 + r) * NDIM + J * 32 + c0 + 0] = -o0;
    W[(size_t)(I * 32 + r) * NDIM + J * 32 + c0 + 1] = -o1;
    W[(size_t)(I * 32 + r) * NDIM + J * 32 + c0 + 2] = -o2;
    W[(size_t)(I * 32 + r) * NDIM + J * 32 + c0 + 3] = -o3;
    __syncthreads();
  }
}

// =====================================================================
// c = -Minv * p   (column sweep, Minv symmetric)
// =====================================================================
__global__ __launch_bounds__(512) void cvec_kernel(const float* __restrict__ Minv,
                                                   const float* __restrict__ p,
                                                   float* __restrict__ c) {
  const int b = blockIdx.x, i = threadIdx.x;
  __shared__ float ps[512];
  ps[i] = p[b * NDIM + i];
  __syncthreads();
  const float* Mb = Minv + (size_t)b * MAT;
  float acc = 0.f;
#pragma unroll 8
  for (int m = 0; m < NDIM; ++m) acc += Mb[m * NDIM + i] * ps[m];
  c[b * NDIM + i] = -acc;
}

// =====================================================================
// 50 ADMM iterations, one workgroup per batch.
//   x' = c + sum_k P1[k][i]*w_k + sigma*sum_k Minv[k][i]*x_k
//   y  = A x' (wave row-dots);  z=clip(y+u);  u+=y-z;  w=z-u
// =====================================================================
__global__ __launch_bounds__(512) void admm_iterate(const float* __restrict__ P1,
                                                    const float* __restrict__ Minv,
                                                    const float* __restrict__ Ain,
                                                    const float* __restrict__ cvec,
                                                    const float* __restrict__ lb,
                                                    const float* __restrict__ ub,
                                                    float* __restrict__ out) {
  const int b = blockIdx.x;
  const int i = threadIdx.x;
  const float* P1b = P1 + (size_t)b * MAT;
  const float* Mb = Minv + (size_t)b * MAT;
  const float* Ab = Ain + (size_t)b * MAT;
  __shared__ float xs[512];
  __shared__ float ws[512];
  __shared__ float ys[512];
  const float ci = cvec[b * NDIM + i];
  const float lbi = lb[b * NDIM + i];
  const float ubi = ub[b * NDIM + i];
  float ui = 0.f;
  xs[i] = 0.f;
  ws[i] = 0.f;
  __syncthreads();
  const int wv = i >> 6, ln = i & 63;
  for (int it = 0; it < 50; ++it) {
    // phase 1: x update (column sweeps, coalesced)
    float accP = 0.f, accS = 0.f;
#pragma unroll 8
    for (int k = 0; k < NDIM; ++k) {
      accP += P1b[k * NDIM + i] * ws[k];
      accS += Mb[k * NDIM + i] * xs[k];
    }
    float xn = ci + accP + SIGMA_F * accS;
    __syncthreads();
    xs[i] = xn;
    __syncthreads();
    // phase 2: y = A * x  (each wave: 64 row dot-products)
    for (int q = 0; q < 64; ++q) {
      const int j = wv * 64 + q;
      const float* Arow = Ab + (size_t)j * NDIM;
      float s = 0.f;
#pragma unroll
      for (int h = 0; h < 8; ++h) s += Arow[h * 64 + ln] * xs[h * 64 + ln];
      for (int off = 32; off > 0; off >>= 1) s += __shfl_down(s, off);
      if (ln == 0) ys[j] = s;
    }
    __syncthreads();
    // phase 3: elementwise updates
    float y = ys[i];
    float zi = fminf(fmaxf(y + ui, lbi), ubi);
    ui = ui + y - zi;
    float wi = zi - ui;
    ws[i] = wi;
    __syncthreads();
  }
  out[b * NDIM + i] = xs[i];
}

// =====================================================================
extern "C" void kernel_launch(void* const* d_in, const int* in_sizes, int n_in,
                              void* d_out, int out_size, void* d_ws, size_t ws_size,
                              hipStream_t stream) {
  const float* Q = (const float*)d_in[0];
  const float* p = (const float*)d_in[1];
  const float* A = (const float*)d_in[2];
  const float* lb = (const float*)d_in[3];
  const float* ub = (const float*)d_in[4];
  float* out = (float*)d_out;

  float* B0 = (float*)d_ws;          // ATA -> M -> L -> Minv
  float* B1 = B0 + BATMAT;           // W -> P1
  float* cbuf = B1 + BATMAT;         // [128*512]
  float* rhobuf = cbuf + NBATCH * NDIM;  // [128]

  // zero W buffer (upper triangle of W must be 0 for the dense syrk)
  hipMemsetAsync(B1, 0, BATMAT * sizeof(float), stream);

  // 1) ATA = A^T A  -> B0   (symmetric: lower tiles + mirror)
  gemm512<0, 1><<<dim3(36, 1, NBATCH), 256, 0, stream>>>(A, A, B0, nullptr);
  // 2) rho[b]
  norms_rho<<<NBATCH, 512, 0, stream>>>(Q, B0, rhobuf);
  // 3) M = Q + rho*ATA + sigma*I   (in place on B0)
  form_m<<<2048, 256, 0, stream>>>(Q, rhobuf, B0);
  // 4) Cholesky in place: B0 lower = L
  cholesky512<<<NBATCH, 256, 0, stream>>>(B0);
  // 5) W = L^{-1} -> B1
  trinv_diag<<<NBATCH, 256, 0, stream>>>(B0, B1);
  trinv_offdiag<<<dim3(15, NBATCH), 256, 0, stream>>>(B0, B1);
  // 6) Minv = W^T W -> B0  (L dead; symmetric)
  gemm512<0, 1><<<dim3(36, 1, NBATCH), 256, 0, stream>>>(B1, B1, B0, nullptr);
  // 7) c = -Minv p
  cvec_kernel<<<NBATCH, 512, 0, stream>>>(B0, p, cbuf);
  // 8) P1 = rho * A * Minv -> B1 (W dead)
  gemm512<1, 0><<<dim3(8, 8, NBATCH), 256, 0, stream>>>(A, B0, B1, rhobuf);
  // 9) 50 ADMM iterations -> out
  admm_iterate<<<NBATCH, 512, 0, stream>>>(B1, B0, A, cbuf, lb, ub, out);
}

// Round 2
// 6149.532 us; speedup vs baseline: 1.5721x; 1.5721x over previous
//
#include <hip/hip_runtime.h>

#define NBATCH 128
#define NDIM 512
static constexpr size_t MAT = (size_t)NDIM * NDIM;      // 262144
static constexpr size_t BATMAT = (size_t)NBATCH * MAT;  // 33554432 floats
#define SIGMA_F 1e-6f

// =====================================================================
// GEMM: C[i][j] = alpha * sum_k OpA(k,i)*OpB(k,j)
//   OpA(k,i) = TA ? A[i*N+k] : A[k*N+i]
//   OpB(k,j) = TB ? B[j*N+k] : B[k*N+j]
//   SYM=1: compute lower tiles (by>=bx) only, mirror into upper.
// =====================================================================
template <int TA, int TB, int SYM>
__global__ __launch_bounds__(256) void gemm512(const float* __restrict__ Ag,
                                               const float* __restrict__ Bg,
                                               float* __restrict__ Cg,
                                               const float* __restrict__ alphaPtr) {
  const int b = blockIdx.z;
  const float* Ab = Ag + (size_t)b * MAT;
  const float* Bb = Bg + (size_t)b * MAT;
  float* Cb = Cg + (size_t)b * MAT;
  int bx, by;
  if (SYM) {
    int t = blockIdx.x;
    by = 0;
    while ((by + 1) * (by + 2) / 2 <= t) ++by;
    bx = t - by * (by + 1) / 2;
  } else {
    bx = blockIdx.x;
    by = blockIdx.y;
  }
  const int i0 = by * 64, j0 = bx * 64;
  __shared__ float As[32][68];
  __shared__ float Bs[32][68];
  const int tid = threadIdx.x;
  const int tx = tid & 15, ty = tid >> 4;
  float acc[4][4] = {};
  for (int k0 = 0; k0 < NDIM; k0 += 32) {
    if (TA == 0) {
      const int kk = tid >> 4, m4 = (tid & 15) << 2;
#pragma unroll
      for (int pp = 0; pp < 2; ++pp) {
        float4 v = *reinterpret_cast<const float4*>(&Ab[(size_t)(k0 + kk + 16 * pp) * NDIM + i0 + m4]);
        *reinterpret_cast<float4*>(&As[kk + 16 * pp][m4]) = v;
      }
    } else {
      const int m = tid >> 3, kq = (tid & 7) << 2;
#pragma unroll
      for (int pp = 0; pp < 2; ++pp) {
        float4 v = *reinterpret_cast<const float4*>(&Ab[(size_t)(i0 + m + 32 * pp) * NDIM + k0 + kq]);
        As[kq + 0][m + 32 * pp] = v.x;
        As[kq + 1][m + 32 * pp] = v.y;
        As[kq + 2][m + 32 * pp] = v.z;
        As[kq + 3][m + 32 * pp] = v.w;
      }
    }
    if (TB == 0) {
      const int kk = tid >> 4, n4 = (tid & 15) << 2;
#pragma unroll
      for (int pp = 0; pp < 2; ++pp) {
        float4 v = *reinterpret_cast<const float4*>(&Bb[(size_t)(k0 + kk + 16 * pp) * NDIM + j0 + n4]);
        *reinterpret_cast<float4*>(&Bs[kk + 16 * pp][n4]) = v;
      }
    } else {
      const int m = tid >> 3, kq = (tid & 7) << 2;
#pragma unroll
      for (int pp = 0; pp < 2; ++pp) {
        float4 v = *reinterpret_cast<const float4*>(&Bb[(size_t)(j0 + m + 32 * pp) * NDIM + k0 + kq]);
        Bs[kq + 0][m + 32 * pp] = v.x;
        Bs[kq + 1][m + 32 * pp] = v.y;
        Bs[kq + 2][m + 32 * pp] = v.z;
        Bs[kq + 3][m + 32 * pp] = v.w;
      }
    }
    __syncthreads();
#pragma unroll
    for (int kk = 0; kk < 32; ++kk) {
      float4 a = *reinterpret_cast<const float4*>(&As[kk][ty << 2]);
      float4 bv = *reinterpret_cast<const float4*>(&Bs[kk][tx << 2]);
      acc[0][0] += a.x * bv.x; acc[0][1] += a.x * bv.y; acc[0][2] += a.x * bv.z; acc[0][3] += a.x * bv.w;
      acc[1][0] += a.y * bv.x; acc[1][1] += a.y * bv.y; acc[1][2] += a.y * bv.z; acc[1][3] += a.y * bv.w;
      acc[2][0] += a.z * bv.x; acc[2][1] += a.z * bv.y; acc[2][2] += a.z * bv.z; acc[2][3] += a.z * bv.w;
      acc[3][0] += a.w * bv.x; acc[3][1] += a.w * bv.y; acc[3][2] += a.w * bv.z; acc[3][3] += a.w * bv.w;
    }
    __syncthreads();
  }
  const float alpha = alphaPtr ? alphaPtr[b] : 1.0f;
#pragma unroll
  for (int r = 0; r < 4; ++r) {
    float4 o = make_float4(alpha * acc[r][0], alpha * acc[r][1], alpha * acc[r][2], alpha * acc[r][3]);
    *reinterpret_cast<float4*>(&Cb[(size_t)(i0 + (ty << 2) + r) * NDIM + j0 + (tx << 2)]) = o;
  }
  if (SYM && bx != by) {
#pragma unroll
    for (int r = 0; r < 4; ++r)
#pragma unroll
      for (int c = 0; c < 4; ++c)
        Cb[(size_t)(j0 + (tx << 2) + c) * NDIM + i0 + (ty << 2) + r] = alpha * acc[r][c];
  }
}

// =====================================================================
// rho[b] = clip( ||Q||_F / ||ATA||_F , 1e-6, 1e6 )
// =====================================================================
__global__ __launch_bounds__(512) void norms_rho(const float* __restrict__ Q,
                                                 const float* __restrict__ ATA,
                                                 float* __restrict__ rho) {
  const int b = blockIdx.x;
  const int tid = threadIdx.x;
  const float* Qb = Q + (size_t)b * MAT;
  const float* Tb = ATA + (size_t)b * MAT;
  double sq = 0.0, st = 0.0;
  for (int e = tid; e < (int)MAT; e += 512) {
    float q = Qb[e];
    float t = Tb[e];
    sq += (double)q * q;
    st += (double)t * t;
  }
  __shared__ double s1[512];
  __shared__ double s2[512];
  s1[tid] = sq;
  s2[tid] = st;
  __syncthreads();
  for (int h = 256; h > 0; h >>= 1) {
    if (tid < h) {
      s1[tid] += s1[tid + h];
      s2[tid] += s2[tid + h];
    }
    __syncthreads();
  }
  if (tid == 0) {
    double r = sqrt(s1[0]) / sqrt(s2[0]);
    r = fmin(fmax(r, 1e-6), 1e6);
    rho[b] = (float)r;
  }
}

// =====================================================================
// M = Q + rho*ATA + sigma*I   (in place on the ATA buffer)
// =====================================================================
__global__ void form_m(const float* __restrict__ Q, const float* __restrict__ rho,
                       float* __restrict__ M) {
  size_t stride = (size_t)gridDim.x * blockDim.x;
  for (size_t e = (size_t)blockIdx.x * blockDim.x + threadIdx.x; e < BATMAT; e += stride) {
    int b = (int)(e >> 18);
    int ij = (int)(e & (MAT - 1));
    int i = ij >> 9, j = ij & 511;
    float v = Q[e] + rho[b] * M[e];
    if (i == j) v += SIGMA_F;
    M[e] = v;
  }
}

// =====================================================================
// Batched in-place Cholesky (lower), blocked NB=32, one block per batch.
// =====================================================================
__global__ __launch_bounds__(256) void cholesky512(float* __restrict__ Mg) {
  float* M = Mg + (size_t)blockIdx.x * MAT;
  __shared__ float D[32][33];
  __shared__ float Di[32][33];
  __shared__ float U[64][33];
  __shared__ float V[64][33];
  __shared__ float Ut[32][68];
  __shared__ float Vt[32][68];
  const int tid = threadIdx.x;
  for (int p = 0; p < 16; ++p) {
    const int k0 = p * 32;
    for (int e = tid; e < 1024; e += 256) {
      int r = e >> 5, c = e & 31;
      D[r][c] = M[(size_t)(k0 + r) * NDIM + k0 + c];
    }
    __syncthreads();
    for (int j = 0; j < 32; ++j) {
      if (tid == 0) D[j][j] = sqrtf(D[j][j]);
      __syncthreads();
      if (tid > j && tid < 32) D[tid][j] /= D[j][j];
      __syncthreads();
      for (int e = tid; e < 1024; e += 256) {
        int r = e >> 5, c = e & 31;
        if (c > j && c <= r) D[r][c] -= D[r][j] * D[c][j];
      }
      __syncthreads();
    }
    for (int e = tid; e < 1024; e += 256) {
      int r = e >> 5, c = e & 31;
      if (c <= r) M[(size_t)(k0 + r) * NDIM + k0 + c] = D[r][c];
    }
    if (tid < 32) {
      int j = tid;
      for (int ii = j; ii < 32; ++ii) {
        float v = (ii == j) ? 1.f : 0.f;
        for (int m = j; m < ii; ++m) v -= D[ii][m] * Di[m][j];
        Di[ii][j] = v / D[ii][ii];
      }
    }
    __syncthreads();
    for (int i0 = k0 + 32; i0 < NDIM; i0 += 64) {
      int rows = min(64, NDIM - i0);
      for (int e = tid; e < rows * 32; e += 256) {
        int r = e >> 5, c = e & 31;
        U[r][c] = M[(size_t)(i0 + r) * NDIM + k0 + c];
      }
      __syncthreads();
      for (int e = tid; e < rows * 32; e += 256) {
        int ii = e >> 5, j = e & 31;
        float s = 0.f;
        for (int m = 0; m <= j; ++m) s += U[ii][m] * Di[j][m];
        V[ii][j] = s;
      }
      __syncthreads();
      for (int e = tid; e < rows * 32; e += 256) {
        int r = e >> 5, c = e & 31;
        M[(size_t)(i0 + r) * NDIM + k0 + c] = V[r][c];
      }
      __syncthreads();
    }
    const int base = k0 + 32;
    const int S = NDIM - base;
    const int T = (S + 63) >> 6;
    const int tx = tid & 15, ty = tid >> 4;
    for (int ti = 0; ti < T; ++ti) {
      for (int tj = 0; tj <= ti; ++tj) {
        const int I0 = base + ti * 64, J0 = base + tj * 64;
        __syncthreads();
        for (int e = tid; e < 2048; e += 256) {
          int rr = e >> 5, mm = e & 31;
          Ut[mm][rr] = (I0 + rr < NDIM) ? M[(size_t)(I0 + rr) * NDIM + k0 + mm] : 0.f;
          Vt[mm][rr] = (J0 + rr < NDIM) ? M[(size_t)(J0 + rr) * NDIM + k0 + mm] : 0.f;
        }
        __syncthreads();
        float acc[4][4] = {};
#pragma unroll
        for (int m = 0; m < 32; ++m) {
          float4 a = *reinterpret_cast<const float4*>(&Ut[m][ty << 2]);
          float4 bv = *reinterpret_cast<const float4*>(&Vt[m][tx << 2]);
          acc[0][0] += a.x * bv.x; acc[0][1] += a.x * bv.y; acc[0][2] += a.x * bv.z; acc[0][3] += a.x * bv.w;
          acc[1][0] += a.y * bv.x; acc[1][1] += a.y * bv.y; acc[1][2] += a.y * bv.z; acc[1][3] += a.y * bv.w;
          acc[2][0] += a.z * bv.x; acc[2][1] += a.z * bv.y; acc[2][2] += a.z * bv.z; acc[2][3] += a.z * bv.w;
          acc[3][0] += a.w * bv.x; acc[3][1] += a.w * bv.y; acc[3][2] += a.w * bv.z; acc[3][3] += a.w * bv.w;
        }
#pragma unroll
        for (int r = 0; r < 4; ++r) {
          int gi = I0 + (ty << 2) + r;
          if (gi < NDIM) {
#pragma unroll
            for (int c = 0; c < 4; ++c) {
              int gj = J0 + (tx << 2) + c;
              if (gj < NDIM) M[(size_t)gi * NDIM + gj] -= acc[r][c];
            }
          }
        }
      }
    }
    __syncthreads();
  }
}

// =====================================================================
// Triangular inverse W = L^{-1} (lower).
// =====================================================================
__global__ __launch_bounds__(256) void trinv_diag(const float* __restrict__ Lg,
                                                  float* __restrict__ Wg) {
  const int b = blockIdx.x;
  const float* L = Lg + (size_t)b * MAT;
  float* W = Wg + (size_t)b * MAT;
  __shared__ float Ld[8][32][33];
  __shared__ float Wd[8][32][33];
  const int g = threadIdx.x >> 5, l = threadIdx.x & 31;
  for (int pass = 0; pass < 2; ++pass) {
    const int bi = pass * 8 + g;
    const int o = bi * 32;
    for (int q = 0; q < 32; ++q) Ld[g][q][l] = L[(size_t)(o + q) * NDIM + o + l];
    __syncthreads();
    for (int ii = l; ii < 32; ++ii) {
      float v = (ii == l) ? 1.f : 0.f;
      for (int m = l; m < ii; ++m) v -= Ld[g][ii][m] * Wd[g][m][l];
      Wd[g][ii][l] = v / Ld[g][ii][ii];
    }
    __syncthreads();
    for (int q = 0; q < 32; ++q)
      if (l <= q) W[(size_t)(o + q) * NDIM + o + l] = Wd[g][q][l];
    __syncthreads();
  }
}

__global__ __launch_bounds__(256) void trinv_offdiag(const float* __restrict__ Lg,
                                                     float* __restrict__ Wg) {
  const int J = blockIdx.x;
  const int b = blockIdx.y;
  const float* L = Lg + (size_t)b * MAT;
  float* W = Wg + (size_t)b * MAT;
  __shared__ float Ls[32][33];
  __shared__ float Ws[32][33];
  __shared__ float Ts[32][33];
  __shared__ float Wi[32][33];
  const int tid = threadIdx.x;
  const int r = tid >> 3, c0 = (tid & 7) << 2;
  for (int I = J + 1; I < 16; ++I) {
    float acc[4] = {0.f, 0.f, 0.f, 0.f};
    for (int K = J; K < I; ++K) {
      __syncthreads();
      for (int e = tid; e < 1024; e += 256) {
        int rr = e >> 5, cc = e & 31;
        Ls[rr][cc] = L[(size_t)(I * 32 + rr) * NDIM + K * 32 + cc];
        Ws[rr][cc] = W[(size_t)(K * 32 + rr) * NDIM + J * 32 + cc];
      }
      __syncthreads();
#pragma unroll 8
      for (int m = 0; m < 32; ++m) {
        float lv = Ls[r][m];
        acc[0] += lv * Ws[m][c0 + 0];
        acc[1] += lv * Ws[m][c0 + 1];
        acc[2] += lv * Ws[m][c0 + 2];
        acc[3] += lv * Ws[m][c0 + 3];
      }
    }
    __syncthreads();
    Ts[r][c0 + 0] = acc[0];
    Ts[r][c0 + 1] = acc[1];
    Ts[r][c0 + 2] = acc[2];
    Ts[r][c0 + 3] = acc[3];
    for (int e = tid; e < 1024; e += 256) {
      int rr = e >> 5, cc = e & 31;
      Wi[rr][cc] = W[(size_t)(I * 32 + rr) * NDIM + I * 32 + cc];
    }
    __syncthreads();
    float o0 = 0.f, o1 = 0.f, o2 = 0.f, o3 = 0.f;
#pragma unroll 8
    for (int m = 0; m < 32; ++m) {
      float wv = Wi[r][m];
      o0 += wv * Ts[m][c0 + 0];
      o1 += wv * Ts[m][c0 + 1];
      o2 += wv * Ts[m][c0 + 2];
      o3 += wv * Ts[m][c0 + 3];
    }
    W[(size_t)(I * 32 + r) * NDIM + J * 32 + c0 + 0] = -o0;
    W[(size_t)(I * 32 + r) * NDIM + J * 32 + c0 + 1] = -o1;
    W[(size_t)(I * 32 + r) * NDIM + J * 32 + c0 + 2] = -o2;
    W[(size_t)(I * 32 + r) * NDIM + J * 32 + c0 + 3] = -o3;
    __syncthreads();
  }
}

// =====================================================================
// c = -Minv * p
// =====================================================================
__global__ __launch_bounds__(512) void cvec_kernel(const float* __restrict__ Minv,
                                                   const float* __restrict__ p,
                                                   float* __restrict__ c) {
  const int b = blockIdx.x, i = threadIdx.x;
  __shared__ float ps[512];
  ps[i] = p[b * NDIM + i];
  __syncthreads();
  const float* Mb = Minv + (size_t)b * MAT;
  float acc = 0.f;
#pragma unroll 8
  for (int m = 0; m < NDIM; ++m) acc += Mb[m * NDIM + i] * ps[m];
  c[b * NDIM + i] = -acc;
}

// =====================================================================
// d = A * c   (wave row-dots)
// =====================================================================
__global__ __launch_bounds__(512) void dvec_kernel(const float* __restrict__ Ain,
                                                   const float* __restrict__ c,
                                                   float* __restrict__ d) {
  const int b = blockIdx.x, i = threadIdx.x;
  __shared__ float cs[512];
  cs[i] = c[b * NDIM + i];
  __syncthreads();
  const int wv = i >> 6, ln = i & 63;
  const float* Ab = Ain + (size_t)b * MAT;
  for (int q = 0; q < 64; ++q) {
    const int j = wv * 64 + q;
    const float* Arow = Ab + (size_t)j * NDIM;
    float s = 0.f;
#pragma unroll
    for (int h = 0; h < 8; ++h) s += Arow[h * 64 + ln] * cs[h * 64 + ln];
    for (int off = 32; off > 0; off >>= 1) s += __shfl_down(s, off);
    if (ln == 0) d[b * NDIM + j] = s;
  }
}

// =====================================================================
// One ADMM iteration in y-space:  y = d + S'w;  z=clip(y+u); u+=y-z; w=z-u
// grid: 256 blocks (2 per batch, j-halved), 512 threads.
// =====================================================================
__global__ __launch_bounds__(512) void admm_step(const float* __restrict__ S,
                                                 const float* __restrict__ dvec,
                                                 const float* __restrict__ lb,
                                                 const float* __restrict__ ub,
                                                 float* __restrict__ wbuf,
                                                 float* __restrict__ ubuf) {
  const int blk = blockIdx.x;
  const int b = blk >> 1, h = blk & 1;
  const int t = threadIdx.x;
  __shared__ float ws_s[512];
  __shared__ float4 part[512];
  ws_s[t] = wbuf[b * NDIM + t];
  __syncthreads();
  const int j4 = t & 63;   // float4 column within this half
  const int ks = t >> 6;   // k-slice 0..7
  const float4* Srow = reinterpret_cast<const float4*>(S + (size_t)b * MAT) +
                       (size_t)(ks * 64) * 128 + h * 64 + j4;
  float4 acc = make_float4(0.f, 0.f, 0.f, 0.f);
#pragma unroll 8
  for (int k = 0; k < 64; ++k) {
    float w = ws_s[ks * 64 + k];
    float4 s = Srow[(size_t)k * 128];
    acc.x += s.x * w;
    acc.y += s.y * w;
    acc.z += s.z * w;
    acc.w += s.w * w;
  }
  part[t] = acc;
  __syncthreads();
  if (t < 64) {
    float4 y = part[t];
#pragma unroll
    for (int s = 1; s < 8; ++s) {
      float4 q = part[s * 64 + t];
      y.x += q.x; y.y += q.y; y.z += q.z; y.w += q.w;
    }
    const size_t off = (size_t)b * NDIM + h * 256 + t * 4;
    float4 dv = *reinterpret_cast<const float4*>(dvec + off);
    float4 uv = *reinterpret_cast<const float4*>(ubuf + off);
    float4 lbv = *reinterpret_cast<const float4*>(lb + off);
    float4 ubv = *reinterpret_cast<const float4*>(ub + off);
    y.x += dv.x; y.y += dv.y; y.z += dv.z; y.w += dv.w;
    float4 zv, wv;
    zv.x = fminf(fmaxf(y.x + uv.x, lbv.x), ubv.x);
    zv.y = fminf(fmaxf(y.y + uv.y, lbv.y), ubv.y);
    zv.z = fminf(fmaxf(y.z + uv.z, lbv.z), ubv.z);
    zv.w = fminf(fmaxf(y.w + uv.w, lbv.w), ubv.w);
    uv.x += y.x - zv.x; uv.y += y.y - zv.y; uv.z += y.z - zv.z; uv.w += y.w - zv.w;
    wv.x = zv.x - uv.x; wv.y = zv.y - uv.y; wv.z = zv.z - uv.z; wv.w = zv.w - uv.w;
    *reinterpret_cast<float4*>(ubuf + off) = uv;
    *reinterpret_cast<float4*>(wbuf + off) = wv;
  }
}

// =====================================================================
// x = c + P1^T w   (P1 = rho*A*Minv; K = rho*Minv*A^T = P1^T)
// =====================================================================
__global__ __launch_bounds__(512) void final_x(const float* __restrict__ P1,
                                               const float* __restrict__ c,
                                               const float* __restrict__ w,
                                               float* __restrict__ out) {
  const int b = blockIdx.x, i = threadIdx.x;
  __shared__ float ws_s[512];
  ws_s[i] = w[b * NDIM + i];
  __syncthreads();
  const float* Pb = P1 + (size_t)b * MAT;
  float acc = 0.f;
#pragma unroll 8
  for (int k = 0; k < NDIM; ++k) acc += Pb[(size_t)k * NDIM + i] * ws_s[k];
  out[b * NDIM + i] = c[b * NDIM + i] + acc;
}

// =====================================================================
extern "C" void kernel_launch(void* const* d_in, const int* in_sizes, int n_in,
                              void* d_out, int out_size, void* d_ws, size_t ws_size,
                              hipStream_t stream) {
  const float* Q = (const float*)d_in[0];
  const float* p = (const float*)d_in[1];
  const float* A = (const float*)d_in[2];
  const float* lb = (const float*)d_in[3];
  const float* ub = (const float*)d_in[4];
  float* out = (float*)d_out;

  float* B0 = (float*)d_ws;              // ATA -> M -> L -> Minv -> S'
  float* B1 = B0 + BATMAT;               // W -> P1
  float* cbuf = B1 + BATMAT;             // [128*512]
  float* dbuf = cbuf + NBATCH * NDIM;    // [128*512]
  float* wbuf = dbuf + NBATCH * NDIM;    // [128*512]
  float* ubuf = wbuf + NBATCH * NDIM;    // [128*512]
  float* rhobuf = ubuf + NBATCH * NDIM;  // [128]

  // zero W buffer (upper triangle must be 0) and the w/u iteration state
  hipMemsetAsync(B1, 0, BATMAT * sizeof(float), stream);
  hipMemsetAsync(wbuf, 0, 2 * NBATCH * NDIM * sizeof(float), stream);

  // 1) ATA = A^T A -> B0
  gemm512<0, 0, 1><<<dim3(36, 1, NBATCH), 256, 0, stream>>>(A, A, B0, nullptr);
  // 2) rho[b]
  norms_rho<<<NBATCH, 512, 0, stream>>>(Q, B0, rhobuf);
  // 3) M = Q + rho*ATA + sigma*I (in place on B0)
  form_m<<<2048, 256, 0, stream>>>(Q, rhobuf, B0);
  // 4) Cholesky in place: B0 lower = L
  cholesky512<<<NBATCH, 256, 0, stream>>>(B0);
  // 5) W = L^{-1} -> B1
  trinv_diag<<<NBATCH, 256, 0, stream>>>(B0, B1);
  trinv_offdiag<<<dim3(15, NBATCH), 256, 0, stream>>>(B0, B1);
  // 6) Minv = W^T W -> B0 (L dead)
  gemm512<0, 0, 1><<<dim3(36, 1, NBATCH), 256, 0, stream>>>(B1, B1, B0, nullptr);
  // 7) c = -Minv p
  cvec_kernel<<<NBATCH, 512, 0, stream>>>(B0, p, cbuf);
  // 8) P1 = rho * A * Minv -> B1 (W dead)
  gemm512<1, 0, 0><<<dim3(8, 8, NBATCH), 256, 0, stream>>>(A, B0, B1, rhobuf);
  // 9) d = A*c
  dvec_kernel<<<NBATCH, 512, 0, stream>>>(A, cbuf, dbuf);
  // 10) S' = P1 * A^T = rho*A*Minv*A^T -> B0 (Minv dead)
  gemm512<1, 1, 1><<<dim3(36, 1, NBATCH), 256, 0, stream>>>(B1, A, B0, nullptr);
  // 11) 49 y-space ADMM iterations (x_50 uses w_49)
  for (int it = 0; it < 49; ++it)
    admm_step<<<2 * NBATCH, 512, 0, stream>>>(B0, dbuf, lb, ub, wbuf, ubuf);
  // 12) x = c + P1^T w_49
  final_x<<<NBATCH, 512, 0, stream>>>(B1, cbuf, wbuf, out);
}